// Round 1
// baseline (235.801 us; speedup 1.0000x reference)
//
#include <hip/hip_runtime.h>
#include <cstddef>

#define ALPHA 0.2f
constexpr int B = 2, N = 8192, F = 256, D = 128;
constexpr int M = B * N;          // 16384 rows total
constexpr int CHUNK = 64;
constexpr int NCH = N / CHUNK;    // 128 chunks per batch

// ---------------- GEMM: fts[m][d] = sum_f seq[m][f] * Wf[f][d] ----------------
__global__ __launch_bounds__(256) void k_gemm(const float* __restrict__ seq,
                                              const float* __restrict__ Wf,
                                              float* __restrict__ fts) {
  __shared__ float As[64][36];     // padded to kill bank conflicts
  __shared__ float Bs[32][128];
  const int m0 = blockIdx.x * 64;
  const int t = threadIdx.x;
  const int colg = t & 31;         // col = colg*4 .. +3
  const int rowg = t >> 5;         // rows rowg*8 .. +7
  float acc[8][4];
#pragma unroll
  for (int r = 0; r < 8; ++r)
#pragma unroll
    for (int c = 0; c < 4; ++c) acc[r][c] = 0.f;

  for (int kc = 0; kc < F; kc += 32) {
#pragma unroll
    for (int it = 0; it < 2; ++it) {           // A tile: 64x32
      int f = t + it * 256;
      int row = f >> 3, wi = f & 7;
      const float4 v = *reinterpret_cast<const float4*>(
          &seq[(size_t)(m0 + row) * F + kc + wi * 4]);
      As[row][wi * 4 + 0] = v.x; As[row][wi * 4 + 1] = v.y;
      As[row][wi * 4 + 2] = v.z; As[row][wi * 4 + 3] = v.w;
    }
#pragma unroll
    for (int it = 0; it < 4; ++it) {           // B tile: 32x128
      int f = t + it * 256;
      int row = f >> 5, c4 = f & 31;
      *reinterpret_cast<float4*>(&Bs[row][c4 * 4]) =
          *reinterpret_cast<const float4*>(&Wf[(size_t)(kc + row) * D + c4 * 4]);
    }
    __syncthreads();
#pragma unroll
    for (int k = 0; k < 32; ++k) {
      float4 b4 = *reinterpret_cast<const float4*>(&Bs[k][colg * 4]);
#pragma unroll
      for (int r = 0; r < 8; ++r) {
        float a = As[rowg * 8 + r][k];
        acc[r][0] += a * b4.x; acc[r][1] += a * b4.y;
        acc[r][2] += a * b4.z; acc[r][3] += a * b4.w;
      }
    }
    __syncthreads();
  }
#pragma unroll
  for (int r = 0; r < 8; ++r) {
    float4 v = {acc[r][0], acc[r][1], acc[r][2], acc[r][3]};
    *reinterpret_cast<float4*>(&fts[(size_t)(m0 + rowg * 8 + r) * D + colg * 4]) = v;
  }
}

// ---------------- f1/f2: per-row dot with w1,w2 (wave per row) ----------------
__global__ __launch_bounds__(256) void k_f1f2(const float* __restrict__ fts,
                                              const float* __restrict__ w1,
                                              const float* __restrict__ b1,
                                              const float* __restrict__ w2,
                                              const float* __restrict__ b2,
                                              float* __restrict__ f1,
                                              float* __restrict__ f2) {
  const int wid = threadIdx.x >> 6;
  const int lane = threadIdx.x & 63;
  const int row = blockIdx.x * 4 + wid;
  const float* p = &fts[(size_t)row * D];
  float x0 = p[lane], x1 = p[lane + 64];
  float d1 = x0 * w1[lane] + x1 * w1[lane + 64];
  float d2 = x0 * w2[lane] + x1 * w2[lane + 64];
#pragma unroll
  for (int off = 32; off > 0; off >>= 1) {
    d1 += __shfl_down(d1, off);
    d2 += __shfl_down(d2, off);
  }
  if (lane == 0) { f1[row] = d1 + b1[0]; f2[row] = d2 + b2[0]; }
}

// ---------------- bitonic sort of f2 (per batch) with payload idx ----------------
__global__ __launch_bounds__(1024) void k_sort(const float* __restrict__ f2,
                                               float* __restrict__ f2s,
                                               int* __restrict__ idxs) {
  __shared__ float key[N];
  __shared__ int val[N];
  const int b = blockIdx.x;
  for (int i = threadIdx.x; i < N; i += 1024) { key[i] = f2[b * N + i]; val[i] = i; }
  __syncthreads();
  for (int k = 2; k <= N; k <<= 1) {
    for (int j = k >> 1; j > 0; j >>= 1) {
      for (int i = threadIdx.x; i < N; i += 1024) {
        int ixj = i ^ j;
        if (ixj > i) {
          bool up = ((i & k) == 0);
          float ki = key[i], kj = key[ixj];
          if ((ki > kj) == up) {
            key[i] = kj; key[ixj] = ki;
            int vi = val[i]; val[i] = val[ixj]; val[ixj] = vi;
          }
        }
      }
      __syncthreads();
    }
  }
  for (int i = threadIdx.x; i < N; i += 1024) { f2s[b * N + i] = key[i]; idxs[b * N + i] = val[i]; }
}

// ---------------- scan phase A: per-chunk weighted sums ----------------
__global__ __launch_bounds__(128) void k_scanA(const float* __restrict__ fts,
                                               const float* __restrict__ f2s,
                                               const int* __restrict__ idxs,
                                               float* __restrict__ chp, float* __restrict__ chn,
                                               float* __restrict__ chps, float* __restrict__ chns) {
  const int b = blockIdx.x / NCH, c = blockIdx.x % NCH;
  const int d = threadIdx.x;
  float ap = 0.f, an = 0.f, sp = 0.f, sn = 0.f;
  for (int s = 0; s < CHUNK; ++s) {
    int t = c * CHUNK + s;
    float k = f2s[b * N + t];
    float wp = expf(k), wn = expf(ALPHA * k);
    int j = idxs[b * N + t];
    float v = fts[((size_t)b * N + j) * D + d];
    ap += wp * v; an += wn * v; sp += wp; sn += wn;
  }
  chp[(b * NCH + c) * D + d] = ap;
  chn[(b * NCH + c) * D + d] = an;
  if (d == 0) { chps[b * NCH + c] = sp; chns[b * NCH + c] = sn; }
}

// ---------------- scan phase B: scan chunk sums (prefix for neg, suffix for pos) ----------------
__global__ __launch_bounds__(128) void k_scanB(const float* __restrict__ chp, const float* __restrict__ chn,
                                               const float* __restrict__ chps, const float* __restrict__ chns,
                                               float* __restrict__ offp, float* __restrict__ offn,
                                               float* __restrict__ offps, float* __restrict__ offns,
                                               float* __restrict__ Spos, float* __restrict__ Sneg,
                                               float* __restrict__ Cpos, float* __restrict__ Cneg) {
  const int b = blockIdx.x, d = threadIdx.x;
  float run = 0.f;
  for (int c = 0; c < NCH; ++c) { offn[(b * NCH + c) * D + d] = run; run += chn[(b * NCH + c) * D + d]; }
  run = 0.f;
  for (int c = NCH - 1; c >= 0; --c) { offp[(b * NCH + c) * D + d] = run; run += chp[(b * NCH + c) * D + d]; }
  Sneg[((size_t)b * (N + 1) + 0) * D + d] = 0.f;
  Spos[((size_t)b * (N + 1) + N) * D + d] = 0.f;
  if (d == 0) {
    float r = 0.f;
    for (int c = 0; c < NCH; ++c) { offns[b * NCH + c] = r; r += chns[b * NCH + c]; }
    r = 0.f;
    for (int c = NCH - 1; c >= 0; --c) { offps[b * NCH + c] = r; r += chps[b * NCH + c]; }
    Cneg[b * (N + 1) + 0] = 0.f;
    Cpos[b * (N + 1) + N] = 0.f;
  }
}

// ---------------- scan phase C: full prefixes within chunks ----------------
__global__ __launch_bounds__(128) void k_scanC(const float* __restrict__ fts,
                                               const float* __restrict__ f2s,
                                               const int* __restrict__ idxs,
                                               const float* __restrict__ offp, const float* __restrict__ offn,
                                               const float* __restrict__ offps, const float* __restrict__ offns,
                                               float* __restrict__ Spos, float* __restrict__ Sneg,
                                               float* __restrict__ Cpos, float* __restrict__ Cneg) {
  const int b = blockIdx.x / NCH, c = blockIdx.x % NCH;
  const int d = threadIdx.x;
  // neg: ascending prefix, stored at k = t+1
  float run = offn[(b * NCH + c) * D + d];
  float srun = offns[b * NCH + c];
  for (int s = 0; s < CHUNK; ++s) {
    int t = c * CHUNK + s;
    float k = f2s[b * N + t];
    float wn = expf(ALPHA * k);
    int j = idxs[b * N + t];
    float v = fts[((size_t)b * N + j) * D + d];
    run += wn * v; srun += wn;
    Sneg[((size_t)b * (N + 1) + t + 1) * D + d] = run;
    if (d == 0) Cneg[b * (N + 1) + t + 1] = srun;
  }
  // pos: descending suffix, stored at k = t
  run = offp[(b * NCH + c) * D + d];
  srun = offps[b * NCH + c];
  for (int s = CHUNK - 1; s >= 0; --s) {
    int t = c * CHUNK + s;
    float k = f2s[b * N + t];
    float wp = expf(k);
    int j = idxs[b * N + t];
    float v = fts[((size_t)b * N + j) * D + d];
    run += wp * v; srun += wp;
    Spos[((size_t)b * (N + 1) + t) * D + d] = run;
    if (d == 0) Cpos[b * (N + 1) + t] = srun;
  }
}

// ---------------- query: binary search + combine ----------------
__global__ __launch_bounds__(128) void k_query(const float* __restrict__ f1,
                                               const float* __restrict__ f2s,
                                               const float* __restrict__ Spos, const float* __restrict__ Sneg,
                                               const float* __restrict__ Cpos, const float* __restrict__ Cneg,
                                               const float* __restrict__ bias,
                                               float* __restrict__ out) {
  const int row = blockIdx.x;  // b*N + i
  const int b = row / N;
  const int d = threadIdx.x;
  const float f1v = f1[row];
  const float th = -f1v;
  const float* ks = &f2s[(size_t)b * N];
  int lo = 0, hi = N;
  while (lo < hi) {
    int mid = (lo + hi) >> 1;
    if (ks[mid] <= th) lo = mid + 1; else hi = mid;
  }
  const int kcut = lo;  // count of f2 <= th  (neg side size)
  const float wqp = expf(f1v), wqn = expf(ALPHA * f1v);
  const float sp = Spos[((size_t)b * (N + 1) + kcut) * D + d];
  const float sn = Sneg[((size_t)b * (N + 1) + kcut) * D + d];
  const float cp = Cpos[b * (N + 1) + kcut];
  const float cn = Cneg[b * (N + 1) + kcut];
  const float denom = wqp * cp + wqn * cn;
  float val = (wqp * sp + wqn * sn) / denom + bias[d];
  out[(size_t)row * D + d] = val >= 0.f ? val : ALPHA * val;
}

extern "C" void kernel_launch(void* const* d_in, const int* in_sizes, int n_in,
                              void* d_out, int out_size, void* d_ws, size_t ws_size,
                              hipStream_t stream) {
  const float* seq  = (const float*)d_in[0];
  const float* Wf   = (const float*)d_in[1];
  const float* w1   = (const float*)d_in[2];
  const float* b1   = (const float*)d_in[3];
  const float* w2   = (const float*)d_in[4];
  const float* b2   = (const float*)d_in[5];
  const float* bias = (const float*)d_in[6];
  float* out = (float*)d_out;

  char* ws = (char*)d_ws;
  size_t off = 0;
  auto alloc = [&](size_t bytes) -> void* {
    void* p = ws + off;
    off = (off + bytes + 255) & ~(size_t)255;
    return p;
  };

  float* fts  = (float*)alloc((size_t)M * D * 4);
  float* f1   = (float*)alloc((size_t)M * 4);
  float* f2   = (float*)alloc((size_t)M * 4);
  float* f2s  = (float*)alloc((size_t)M * 4);
  int*   idxs = (int*)  alloc((size_t)M * 4);
  float* chp  = (float*)alloc((size_t)B * NCH * D * 4);
  float* chn  = (float*)alloc((size_t)B * NCH * D * 4);
  float* chps = (float*)alloc((size_t)B * NCH * 4);
  float* chns = (float*)alloc((size_t)B * NCH * 4);
  float* offp = (float*)alloc((size_t)B * NCH * D * 4);
  float* offn = (float*)alloc((size_t)B * NCH * D * 4);
  float* offps= (float*)alloc((size_t)B * NCH * 4);
  float* offns= (float*)alloc((size_t)B * NCH * 4);
  float* Spos = (float*)alloc((size_t)B * (N + 1) * D * 4);
  float* Sneg = (float*)alloc((size_t)B * (N + 1) * D * 4);
  float* Cpos = (float*)alloc((size_t)B * (N + 1) * 4);
  float* Cneg = (float*)alloc((size_t)B * (N + 1) * 4);

  hipLaunchKernelGGL(k_gemm, dim3(M / 64), dim3(256), 0, stream, seq, Wf, fts);
  hipLaunchKernelGGL(k_f1f2, dim3(M / 4), dim3(256), 0, stream, fts, w1, b1, w2, b2, f1, f2);
  hipLaunchKernelGGL(k_sort, dim3(B), dim3(1024), 0, stream, f2, f2s, idxs);
  hipLaunchKernelGGL(k_scanA, dim3(B * NCH), dim3(128), 0, stream, fts, f2s, idxs, chp, chn, chps, chns);
  hipLaunchKernelGGL(k_scanB, dim3(B), dim3(128), 0, stream, chp, chn, chps, chns,
                     offp, offn, offps, offns, Spos, Sneg, Cpos, Cneg);
  hipLaunchKernelGGL(k_scanC, dim3(B * NCH), dim3(128), 0, stream, fts, f2s, idxs,
                     offp, offn, offps, offns, Spos, Sneg, Cpos, Cneg);
  hipLaunchKernelGGL(k_query, dim3(M), dim3(128), 0, stream, f1, f2s, Spos, Sneg, Cpos, Cneg, bias, out);
}

// Round 2
// 130.747 us; speedup vs baseline: 1.8035x; 1.8035x over previous
//
#include <hip/hip_runtime.h>
#include <cstddef>

#define ALPHA 0.2f
constexpr int B = 2, N = 8192, F = 256, D = 128;
constexpr int M = B * N;          // 16384 rows total
constexpr int CHUNK = 64;
constexpr int NCH = N / CHUNK;    // 128 chunks per batch
constexpr int NB = 2048;          // value buckets per batch
constexpr int SUB = 256;          // elements per sub-block for stable scatter
constexpr int P = N / SUB;        // 32 sub-blocks per batch

// ---- monotone float<->uint encoding for atomic min/max ----
__device__ inline unsigned fenc(float x) {
  unsigned u = __float_as_uint(x);
  return (u & 0x80000000u) ? ~u : (u | 0x80000000u);
}
__device__ inline float fdec(unsigned u) {
  return (u & 0x80000000u) ? __uint_as_float(u ^ 0x80000000u) : __uint_as_float(~u);
}
__device__ inline void bparams(const unsigned* __restrict__ mmu, int b, float& mn, float& scale) {
  mn = fdec(mmu[b * 2 + 0]);
  float mx = fdec(mmu[b * 2 + 1]);
  float range = mx - mn;
  scale = ((float)NB - 0.001f) / fmaxf(range, 1e-30f);
}
__device__ inline int bucket_of(float x, float mn, float scale) {
  int g = (int)((x - mn) * scale);
  return g < 0 ? 0 : (g > NB - 1 ? NB - 1 : g);
}

// ---------------- GEMM: fts[m][d] = sum_f seq[m][f] * Wf[f][d] ----------------
__global__ __launch_bounds__(256) void k_gemm(const float* __restrict__ seq,
                                              const float* __restrict__ Wf,
                                              float* __restrict__ fts) {
  __shared__ float As[64][36];
  __shared__ float Bs[32][128];
  const int m0 = blockIdx.x * 64;
  const int t = threadIdx.x;
  const int colg = t & 31;
  const int rowg = t >> 5;
  float acc[8][4];
#pragma unroll
  for (int r = 0; r < 8; ++r)
#pragma unroll
    for (int c = 0; c < 4; ++c) acc[r][c] = 0.f;

  for (int kc = 0; kc < F; kc += 32) {
#pragma unroll
    for (int it = 0; it < 2; ++it) {
      int f = t + it * 256;
      int row = f >> 3, wi = f & 7;
      const float4 v = *reinterpret_cast<const float4*>(
          &seq[(size_t)(m0 + row) * F + kc + wi * 4]);
      As[row][wi * 4 + 0] = v.x; As[row][wi * 4 + 1] = v.y;
      As[row][wi * 4 + 2] = v.z; As[row][wi * 4 + 3] = v.w;
    }
#pragma unroll
    for (int it = 0; it < 4; ++it) {
      int f = t + it * 256;
      int row = f >> 5, c4 = f & 31;
      *reinterpret_cast<float4*>(&Bs[row][c4 * 4]) =
          *reinterpret_cast<const float4*>(&Wf[(size_t)(kc + row) * D + c4 * 4]);
    }
    __syncthreads();
#pragma unroll
    for (int k = 0; k < 32; ++k) {
      float4 b4 = *reinterpret_cast<const float4*>(&Bs[k][colg * 4]);
#pragma unroll
      for (int r = 0; r < 8; ++r) {
        float a = As[rowg * 8 + r][k];
        acc[r][0] += a * b4.x; acc[r][1] += a * b4.y;
        acc[r][2] += a * b4.z; acc[r][3] += a * b4.w;
      }
    }
    __syncthreads();
  }
#pragma unroll
  for (int r = 0; r < 8; ++r) {
    float4 v = {acc[r][0], acc[r][1], acc[r][2], acc[r][3]};
    *reinterpret_cast<float4*>(&fts[(size_t)(m0 + rowg * 8 + r) * D + colg * 4]) = v;
  }
}

// ---------------- f1/f2 ----------------
__global__ __launch_bounds__(256) void k_f1f2(const float* __restrict__ fts,
                                              const float* __restrict__ w1,
                                              const float* __restrict__ b1,
                                              const float* __restrict__ w2,
                                              const float* __restrict__ b2,
                                              float* __restrict__ f1,
                                              float* __restrict__ f2) {
  const int wid = threadIdx.x >> 6;
  const int lane = threadIdx.x & 63;
  const int row = blockIdx.x * 4 + wid;
  const float* p = &fts[(size_t)row * D];
  float x0 = p[lane], x1 = p[lane + 64];
  float d1 = x0 * w1[lane] + x1 * w1[lane + 64];
  float d2 = x0 * w2[lane] + x1 * w2[lane + 64];
#pragma unroll
  for (int off = 32; off > 0; off >>= 1) {
    d1 += __shfl_down(d1, off);
    d2 += __shfl_down(d2, off);
  }
  if (lane == 0) { f1[row] = d1 + b1[0]; f2[row] = d2 + b2[0]; }
}

// ---------------- init: zero ghist, seed min/max ----------------
__global__ __launch_bounds__(1024) void k_init(int* __restrict__ ghist, unsigned* __restrict__ mmu) {
  int t = blockIdx.x * blockDim.x + threadIdx.x;
  int stride = gridDim.x * blockDim.x;
  for (int i = t; i < B * NB; i += stride) ghist[i] = 0;
  if (t < B) { mmu[t * 2 + 0] = 0xFFFFFFFFu; mmu[t * 2 + 1] = 0u; }
}

// ---------------- min/max of f2 per batch ----------------
__global__ __launch_bounds__(256) void k_minmax(const float* __restrict__ f2, unsigned* __restrict__ mmu) {
  __shared__ unsigned smn[256], smx[256];
  const int b = blockIdx.x / P, p = blockIdx.x % P;
  const int t = threadIdx.x;
  unsigned e = fenc(f2[b * N + p * SUB + t]);
  smn[t] = e; smx[t] = e;
  __syncthreads();
  for (int s = 128; s > 0; s >>= 1) {
    if (t < s) {
      smn[t] = min(smn[t], smn[t + s]);
      smx[t] = max(smx[t], smx[t + s]);
    }
    __syncthreads();
  }
  if (t == 0) {
    atomicMin(&mmu[b * 2 + 0], smn[0]);
    atomicMax(&mmu[b * 2 + 1], smx[0]);
  }
}

// ---------------- histogram per sub-block + global (integer, deterministic) ----------------
__global__ __launch_bounds__(256) void k_hist(const float* __restrict__ f2,
                                              const unsigned* __restrict__ mmu,
                                              int* __restrict__ bid,
                                              int* __restrict__ histcnt,
                                              int* __restrict__ ghist) {
  __shared__ int hist[NB];
  const int b = blockIdx.x / P, p = blockIdx.x % P;
  const int t = threadIdx.x;
  for (int i = t; i < NB; i += 256) hist[i] = 0;
  float mn, scale; bparams(mmu, b, mn, scale);
  const int j = p * SUB + t;
  float x = f2[b * N + j];
  int g = bucket_of(x, mn, scale);
  bid[b * N + j] = g;
  __syncthreads();
  atomicAdd(&hist[g], 1);
  __syncthreads();
  for (int i = t; i < NB; i += 256) {
    int c = hist[i];
    histcnt[((size_t)(b * P + p)) * NB + i] = c;
    if (c) atomicAdd(&ghist[b * NB + i], c);
  }
}

// ---------------- exclusive scan of bucket counts (Blelloch, per batch) ----------------
__global__ __launch_bounds__(1024) void k_bscan(const int* __restrict__ ghist, int* __restrict__ bstart) {
  __shared__ int s[NB];
  const int b = blockIdx.x, t = threadIdx.x;
  s[2 * t] = ghist[b * NB + 2 * t];
  s[2 * t + 1] = ghist[b * NB + 2 * t + 1];
  int offset = 1;
  for (int d = NB >> 1; d > 0; d >>= 1) {
    __syncthreads();
    if (t < d) { int ai = offset * (2 * t + 1) - 1, bi = offset * (2 * t + 2) - 1; s[bi] += s[ai]; }
    offset <<= 1;
  }
  __syncthreads();
  if (t == 0) { bstart[b * (NB + 1) + NB] = s[NB - 1]; s[NB - 1] = 0; }
  for (int d = 1; d < NB; d <<= 1) {
    offset >>= 1;
    __syncthreads();
    if (t < d) {
      int ai = offset * (2 * t + 1) - 1, bi = offset * (2 * t + 2) - 1;
      int tmp = s[ai]; s[ai] = s[bi]; s[bi] += tmp;
    }
  }
  __syncthreads();
  bstart[b * (NB + 1) + 2 * t] = s[2 * t];
  bstart[b * (NB + 1) + 2 * t + 1] = s[2 * t + 1];
}

// ---------------- stable deterministic scatter into bucket-grouped order ----------------
__global__ __launch_bounds__(256) void k_scatter(const float* __restrict__ f2,
                                                 const int* __restrict__ bid,
                                                 const int* __restrict__ histcnt,
                                                 const int* __restrict__ bstart,
                                                 float* __restrict__ f2s,
                                                 int* __restrict__ idxs) {
  __shared__ int bids[SUB];
  const int b = blockIdx.x / P, p = blockIdx.x % P;
  const int t = threadIdx.x;
  const int j = p * SUB + t;
  const int g = bid[b * N + j];
  bids[t] = g;
  __syncthreads();
  int off = bstart[b * (NB + 1) + g];
  for (int pp = 0; pp < p; ++pp) off += histcnt[((size_t)(b * P + pp)) * NB + g];
  for (int jj = 0; jj < t; ++jj) off += (bids[jj] == g);
  f2s[b * N + off] = f2[b * N + j];
  idxs[b * N + off] = j;
}

// ---------------- scan phase A: per-chunk weighted sums ----------------
__global__ __launch_bounds__(128) void k_scanA(const float* __restrict__ fts,
                                               const float* __restrict__ f2s,
                                               const int* __restrict__ idxs,
                                               float* __restrict__ chp, float* __restrict__ chn,
                                               float* __restrict__ chps, float* __restrict__ chns) {
  const int b = blockIdx.x / NCH, c = blockIdx.x % NCH;
  const int d = threadIdx.x;
  float ap = 0.f, an = 0.f, sp = 0.f, sn = 0.f;
  for (int s = 0; s < CHUNK; ++s) {
    int t = c * CHUNK + s;
    float k = f2s[b * N + t];
    float wp = expf(k), wn = expf(ALPHA * k);
    int j = idxs[b * N + t];
    float v = fts[((size_t)b * N + j) * D + d];
    ap += wp * v; an += wn * v; sp += wp; sn += wn;
  }
  chp[(b * NCH + c) * D + d] = ap;
  chn[(b * NCH + c) * D + d] = an;
  if (d == 0) { chps[b * NCH + c] = sp; chns[b * NCH + c] = sn; }
}

// ---------------- scan phase B ----------------
__global__ __launch_bounds__(128) void k_scanB(const float* __restrict__ chp, const float* __restrict__ chn,
                                               const float* __restrict__ chps, const float* __restrict__ chns,
                                               float* __restrict__ offp, float* __restrict__ offn,
                                               float* __restrict__ offps, float* __restrict__ offns,
                                               float* __restrict__ Spos, float* __restrict__ Sneg,
                                               float* __restrict__ Cpos, float* __restrict__ Cneg) {
  const int b = blockIdx.x, d = threadIdx.x;
  float run = 0.f;
  for (int c = 0; c < NCH; ++c) { offn[(b * NCH + c) * D + d] = run; run += chn[(b * NCH + c) * D + d]; }
  run = 0.f;
  for (int c = NCH - 1; c >= 0; --c) { offp[(b * NCH + c) * D + d] = run; run += chp[(b * NCH + c) * D + d]; }
  Sneg[((size_t)b * (N + 1) + 0) * D + d] = 0.f;
  Spos[((size_t)b * (N + 1) + N) * D + d] = 0.f;
  if (d == 0) {
    float r = 0.f;
    for (int c = 0; c < NCH; ++c) { offns[b * NCH + c] = r; r += chns[b * NCH + c]; }
    r = 0.f;
    for (int c = NCH - 1; c >= 0; --c) { offps[b * NCH + c] = r; r += chps[b * NCH + c]; }
    Cneg[b * (N + 1) + 0] = 0.f;
    Cpos[b * (N + 1) + N] = 0.f;
  }
}

// ---------------- scan phase C: element-level prefixes ----------------
__global__ __launch_bounds__(128) void k_scanC(const float* __restrict__ fts,
                                               const float* __restrict__ f2s,
                                               const int* __restrict__ idxs,
                                               const float* __restrict__ offp, const float* __restrict__ offn,
                                               const float* __restrict__ offps, const float* __restrict__ offns,
                                               float* __restrict__ Spos, float* __restrict__ Sneg,
                                               float* __restrict__ Cpos, float* __restrict__ Cneg) {
  const int b = blockIdx.x / NCH, c = blockIdx.x % NCH;
  const int d = threadIdx.x;
  float run = offn[(b * NCH + c) * D + d];
  float srun = offns[b * NCH + c];
  for (int s = 0; s < CHUNK; ++s) {
    int t = c * CHUNK + s;
    float k = f2s[b * N + t];
    float wn = expf(ALPHA * k);
    int j = idxs[b * N + t];
    float v = fts[((size_t)b * N + j) * D + d];
    run += wn * v; srun += wn;
    Sneg[((size_t)b * (N + 1) + t + 1) * D + d] = run;
    if (d == 0) Cneg[b * (N + 1) + t + 1] = srun;
  }
  run = offp[(b * NCH + c) * D + d];
  srun = offps[b * NCH + c];
  for (int s = CHUNK - 1; s >= 0; --s) {
    int t = c * CHUNK + s;
    float k = f2s[b * N + t];
    float wp = expf(k);
    int j = idxs[b * N + t];
    float v = fts[((size_t)b * N + j) * D + d];
    run += wp * v; srun += wp;
    Spos[((size_t)b * (N + 1) + t) * D + d] = run;
    if (d == 0) Cpos[b * (N + 1) + t] = srun;
  }
}

// ---------------- query: bucket lookup + boundary resolve + combine ----------------
__global__ __launch_bounds__(128) void k_query(const float* __restrict__ f1,
                                               const float* __restrict__ f2s,
                                               const int* __restrict__ idxs,
                                               const float* __restrict__ fts,
                                               const int* __restrict__ bstart,
                                               const unsigned* __restrict__ mmu,
                                               const float* __restrict__ Spos, const float* __restrict__ Sneg,
                                               const float* __restrict__ Cpos, const float* __restrict__ Cneg,
                                               const float* __restrict__ bias,
                                               float* __restrict__ out) {
  const int row = blockIdx.x;  // b*N + i
  const int b = row / N;
  const int d = threadIdx.x;
  const float f1v = f1[row];
  const float th = -f1v;
  float mn, scale; bparams(mmu, b, mn, scale);
  const int g = bucket_of(th, mn, scale);
  const int base = bstart[b * (NB + 1) + g];
  const int end  = bstart[b * (NB + 1) + g + 1];
  float sp = Spos[((size_t)b * (N + 1) + end) * D + d];
  float sn = Sneg[((size_t)b * (N + 1) + base) * D + d];
  float cp = Cpos[b * (N + 1) + end];
  float cn = Cneg[b * (N + 1) + base];
  for (int e = base; e < end; ++e) {
    float key = f2s[b * N + e];
    int j = idxs[b * N + e];
    float v = fts[((size_t)b * N + j) * D + d];
    if (key <= th) { float w = expf(ALPHA * key); sn += w * v; cn += w; }
    else           { float w = expf(key);          sp += w * v; cp += w; }
  }
  const float wqp = expf(f1v), wqn = expf(ALPHA * f1v);
  const float denom = wqp * cp + wqn * cn;
  float val = (wqp * sp + wqn * sn) / denom + bias[d];
  out[(size_t)row * D + d] = val >= 0.f ? val : ALPHA * val;
}

extern "C" void kernel_launch(void* const* d_in, const int* in_sizes, int n_in,
                              void* d_out, int out_size, void* d_ws, size_t ws_size,
                              hipStream_t stream) {
  const float* seq  = (const float*)d_in[0];
  const float* Wf   = (const float*)d_in[1];
  const float* w1   = (const float*)d_in[2];
  const float* b1   = (const float*)d_in[3];
  const float* w2   = (const float*)d_in[4];
  const float* b2   = (const float*)d_in[5];
  const float* bias = (const float*)d_in[6];
  float* out = (float*)d_out;

  char* ws = (char*)d_ws;
  size_t off = 0;
  auto alloc = [&](size_t bytes) -> void* {
    void* p = ws + off;
    off = (off + bytes + 255) & ~(size_t)255;
    return p;
  };

  float* fts   = (float*)alloc((size_t)M * D * 4);
  float* f1    = (float*)alloc((size_t)M * 4);
  float* f2    = (float*)alloc((size_t)M * 4);
  float* f2s   = (float*)alloc((size_t)M * 4);
  int*   idxs  = (int*)  alloc((size_t)M * 4);
  float* chp   = (float*)alloc((size_t)B * NCH * D * 4);
  float* chn   = (float*)alloc((size_t)B * NCH * D * 4);
  float* chps  = (float*)alloc((size_t)B * NCH * 4);
  float* chns  = (float*)alloc((size_t)B * NCH * 4);
  float* offp  = (float*)alloc((size_t)B * NCH * D * 4);
  float* offn  = (float*)alloc((size_t)B * NCH * D * 4);
  float* offps = (float*)alloc((size_t)B * NCH * 4);
  float* offns = (float*)alloc((size_t)B * NCH * 4);
  float* Spos  = (float*)alloc((size_t)B * (N + 1) * D * 4);
  float* Sneg  = (float*)alloc((size_t)B * (N + 1) * D * 4);
  float* Cpos  = (float*)alloc((size_t)B * (N + 1) * 4);
  float* Cneg  = (float*)alloc((size_t)B * (N + 1) * 4);
  int*   bid     = (int*)     alloc((size_t)M * 4);
  int*   histcnt = (int*)     alloc((size_t)B * P * NB * 4);
  int*   ghist   = (int*)     alloc((size_t)B * NB * 4);
  int*   bstart  = (int*)     alloc((size_t)B * (NB + 1) * 4);
  unsigned* mmu  = (unsigned*)alloc((size_t)B * 2 * 4);

  hipLaunchKernelGGL(k_gemm, dim3(M / 64), dim3(256), 0, stream, seq, Wf, fts);
  hipLaunchKernelGGL(k_f1f2, dim3(M / 4), dim3(256), 0, stream, fts, w1, b1, w2, b2, f1, f2);
  hipLaunchKernelGGL(k_init, dim3(4), dim3(1024), 0, stream, ghist, mmu);
  hipLaunchKernelGGL(k_minmax, dim3(B * P), dim3(256), 0, stream, f2, mmu);
  hipLaunchKernelGGL(k_hist, dim3(B * P), dim3(256), 0, stream, f2, mmu, bid, histcnt, ghist);
  hipLaunchKernelGGL(k_bscan, dim3(B), dim3(1024), 0, stream, ghist, bstart);
  hipLaunchKernelGGL(k_scatter, dim3(B * P), dim3(256), 0, stream, f2, bid, histcnt, bstart, f2s, idxs);
  hipLaunchKernelGGL(k_scanA, dim3(B * NCH), dim3(128), 0, stream, fts, f2s, idxs, chp, chn, chps, chns);
  hipLaunchKernelGGL(k_scanB, dim3(B), dim3(128), 0, stream, chp, chn, chps, chns,
                     offp, offn, offps, offns, Spos, Sneg, Cpos, Cneg);
  hipLaunchKernelGGL(k_scanC, dim3(B * NCH), dim3(128), 0, stream, fts, f2s, idxs,
                     offp, offn, offps, offns, Spos, Sneg, Cpos, Cneg);
  hipLaunchKernelGGL(k_query, dim3(M), dim3(128), 0, stream, f1, f2s, idxs, fts, bstart, mmu,
                     Spos, Sneg, Cpos, Cneg, bias, out);
}